// Round 1
// baseline (431.666 us; speedup 1.0000x reference)
//
#include <hip/hip_runtime.h>
#include <hip/hip_bf16.h>
#include <math.h>

#define B 128
#define C 128
#define HW 4096   // 64*64
#define K_TOP 6

// ---------------------------------------------------------------------------
// Kernel A: one block per (b,c). Reads the 4096-float slice (float4), writes
// zeros to the corresponding output slice, and reduces max + first-argmax.
// Tie-break: lowest flat index wins (jnp.argmax / torch first-max semantics).
// ---------------------------------------------------------------------------
__global__ __launch_bounds__(256) void pool_zero_kernel(
        const float* __restrict__ act,
        float* __restrict__ out,
        float* __restrict__ pooled,
        int* __restrict__ pidx) {
    const int bc = blockIdx.x;
    const size_t base = (size_t)bc * HW;
    const float4* __restrict__ src = (const float4*)(act + base);
    float4* __restrict__ dst = (float4*)(out + base);
    const int tid = threadIdx.x;

    float best = -INFINITY;
    int bestIdx = 0;
    const float4 zero = make_float4(0.f, 0.f, 0.f, 0.f);

#pragma unroll
    for (int r = 0; r < 4; ++r) {
        const int p = tid + r * 256;          // float4 index, increasing per thread
        const float4 v = src[p];
        dst[p] = zero;                        // fused zero-fill of the output
        const int ei = p * 4;
        // scan order within a thread is increasing index -> strict > keeps first max
        if (v.x > best) { best = v.x; bestIdx = ei;     }
        if (v.y > best) { best = v.y; bestIdx = ei + 1; }
        if (v.z > best) { best = v.z; bestIdx = ei + 2; }
        if (v.w > best) { best = v.w; bestIdx = ei + 3; }
    }

    // wave (64-lane) reduction with lowest-index tie-break
#pragma unroll
    for (int off = 32; off >= 1; off >>= 1) {
        const float ov = __shfl_down(best, off);
        const int   oi = __shfl_down(bestIdx, off);
        if (ov > best || (ov == best && oi < bestIdx)) { best = ov; bestIdx = oi; }
    }

    __shared__ float sv[4];
    __shared__ int   si[4];
    const int wave = tid >> 6;
    const int lane = tid & 63;
    if (lane == 0) { sv[wave] = best; si[wave] = bestIdx; }
    __syncthreads();
    if (tid == 0) {
        float bv = sv[0]; int bi = si[0];
#pragma unroll
        for (int w = 1; w < 4; ++w) {
            if (sv[w] > bv || (sv[w] == bv && si[w] < bi)) { bv = sv[w]; bi = si[w]; }
        }
        pooled[bc] = bv;
        pidx[bc]   = bi;
    }
}

// ---------------------------------------------------------------------------
// Kernel B: one wave per feature c. Iteratively extract the top-6 pooled
// values over the batch dim (lowest-batch-index tie-break, matching
// jax.lax.top_k stable tie order) and scatter them into the zeroed output.
// ---------------------------------------------------------------------------
__global__ __launch_bounds__(64) void topk_scatter_kernel(
        const float* __restrict__ pooled,
        const int* __restrict__ pidx,
        float* __restrict__ out) {
    const int c = blockIdx.x;
    const int lane = threadIdx.x;

    // each lane holds two batch candidates: lane and lane+64
    float v0 = pooled[(size_t)lane * C + c];
    float v1 = pooled[(size_t)(lane + 64) * C + c];
    const int b0 = lane;
    const int b1 = lane + 64;

    for (int k = 0; k < K_TOP; ++k) {
        // per-lane best; b0 < b1 so >= prefers lower batch on tie
        float mv; int mb;
        if (v0 >= v1) { mv = v0; mb = b0; } else { mv = v1; mb = b1; }

        float rv = mv; int rb = mb;
#pragma unroll
        for (int off = 32; off >= 1; off >>= 1) {
            const float ov = __shfl_down(rv, off);
            const int   ob = __shfl_down(rb, off);
            if (ov > rv || (ov == rv && ob < rb)) { rv = ov; rb = ob; }
        }
        rv = __shfl(rv, 0);
        rb = __shfl(rb, 0);

        if (lane == 0) {
            const int hw = pidx[(size_t)rb * C + c];
            out[(size_t)rb * (C * HW) + (size_t)c * HW + (size_t)hw] = rv;
        }

        // invalidate the selected candidate
        if (rb == b0) v0 = -INFINITY;
        else if (rb == b1) v1 = -INFINITY;
    }
}

extern "C" void kernel_launch(void* const* d_in, const int* in_sizes, int n_in,
                              void* d_out, int out_size, void* d_ws, size_t ws_size,
                              hipStream_t stream) {
    const float* act = (const float*)d_in[0];
    float* out = (float*)d_out;

    // workspace: pooled[B*C] floats + pidx[B*C] ints = 128 KiB
    float* pooled = (float*)d_ws;
    int*   pidx   = (int*)(pooled + B * C);

    pool_zero_kernel<<<B * C, 256, 0, stream>>>(act, out, pooled, pidx);
    topk_scatter_kernel<<<C, 64, 0, stream>>>(pooled, pidx, out);
}

// Round 3
// 415.494 us; speedup vs baseline: 1.0389x; 1.0389x over previous
//
#include <hip/hip_runtime.h>
#include <hip/hip_bf16.h>
#include <math.h>

#define B 128
#define C 128
#define HW 4096   // 64*64
#define K_TOP 6

// native clang vector type — accepted by __builtin_nontemporal_load/store
typedef float vfloat4 __attribute__((ext_vector_type(4)));

// ---------------------------------------------------------------------------
// Kernel A: one block per (b,c). Streams the 4096-float slice (nontemporal
// float4 loads), streams zeros to the output slice (nontemporal stores), and
// reduces max + first-argmax. Tie-break: lowest flat index wins (jnp.argmax
// first-max semantics). pooled/pidx stored transposed [C][B] so kernel B
// reads coalesced.
// ---------------------------------------------------------------------------
__global__ __launch_bounds__(256) void pool_zero_kernel(
        const float* __restrict__ act,
        float* __restrict__ out,
        float* __restrict__ pooledT,
        int* __restrict__ pidxT) {
    const int bc = blockIdx.x;
    const size_t base = (size_t)bc * HW;
    const vfloat4* __restrict__ src = (const vfloat4*)(act + base);
    vfloat4* __restrict__ dst = (vfloat4*)(out + base);
    const int tid = threadIdx.x;

    float best = -INFINITY;
    int bestIdx = 0;
    const vfloat4 zero = (vfloat4)(0.f);

#pragma unroll
    for (int r = 0; r < 4; ++r) {
        const int p = tid + r * 256;          // float4 index, increasing per thread
        const vfloat4 v = __builtin_nontemporal_load(&src[p]);
        __builtin_nontemporal_store(zero, &dst[p]);   // fused zero-fill
        const int ei = p * 4;
        // scan order within a thread is increasing index -> strict > keeps first max
        if (v.x > best) { best = v.x; bestIdx = ei;     }
        if (v.y > best) { best = v.y; bestIdx = ei + 1; }
        if (v.z > best) { best = v.z; bestIdx = ei + 2; }
        if (v.w > best) { best = v.w; bestIdx = ei + 3; }
    }

    // wave (64-lane) reduction with lowest-index tie-break
#pragma unroll
    for (int off = 32; off >= 1; off >>= 1) {
        const float ov = __shfl_down(best, off);
        const int   oi = __shfl_down(bestIdx, off);
        if (ov > best || (ov == best && oi < bestIdx)) { best = ov; bestIdx = oi; }
    }

    __shared__ float sv[4];
    __shared__ int   si[4];
    const int wave = tid >> 6;
    const int lane = tid & 63;
    if (lane == 0) { sv[wave] = best; si[wave] = bestIdx; }
    __syncthreads();
    if (tid == 0) {
        float bv = sv[0]; int bi = si[0];
#pragma unroll
        for (int w = 1; w < 4; ++w) {
            if (sv[w] > bv || (sv[w] == bv && si[w] < bi)) { bv = sv[w]; bi = si[w]; }
        }
        const int b = bc / C;
        const int c = bc % C;
        pooledT[(size_t)c * B + b] = bv;   // transposed: [C][B]
        pidxT[(size_t)c * B + b]   = bi;
    }
}

// ---------------------------------------------------------------------------
// Kernel B: one wave per feature c. Iteratively extract the top-6 pooled
// values over the batch dim (lowest-batch-index tie-break, matching
// jax.lax.top_k stable tie order) and scatter them into the zeroed output.
// pooledT/pidxT are [C][B] so the 128-value row is contiguous.
// ---------------------------------------------------------------------------
__global__ __launch_bounds__(64) void topk_scatter_kernel(
        const float* __restrict__ pooledT,
        const int* __restrict__ pidxT,
        float* __restrict__ out) {
    const int c = blockIdx.x;
    const int lane = threadIdx.x;
    const float* row = pooledT + (size_t)c * B;

    // each lane holds two batch candidates: lane and lane+64
    float v0 = row[lane];
    float v1 = row[lane + 64];
    const int b0 = lane;
    const int b1 = lane + 64;

    for (int k = 0; k < K_TOP; ++k) {
        // per-lane best; b0 < b1 so >= prefers lower batch on tie
        float mv; int mb;
        if (v0 >= v1) { mv = v0; mb = b0; } else { mv = v1; mb = b1; }

        float rv = mv; int rb = mb;
#pragma unroll
        for (int off = 32; off >= 1; off >>= 1) {
            const float ov = __shfl_down(rv, off);
            const int   ob = __shfl_down(rb, off);
            if (ov > rv || (ov == rv && ob < rb)) { rv = ov; rb = ob; }
        }
        rv = __shfl(rv, 0);
        rb = __shfl(rb, 0);

        if (lane == 0) {
            const int hw = pidxT[(size_t)c * B + rb];
            out[(size_t)rb * (C * HW) + (size_t)c * HW + (size_t)hw] = rv;
        }

        // invalidate the selected candidate
        if (rb == b0) v0 = -INFINITY;
        else if (rb == b1) v1 = -INFINITY;
    }
}

extern "C" void kernel_launch(void* const* d_in, const int* in_sizes, int n_in,
                              void* d_out, int out_size, void* d_ws, size_t ws_size,
                              hipStream_t stream) {
    const float* act = (const float*)d_in[0];
    float* out = (float*)d_out;

    // workspace: pooledT[C*B] floats + pidxT[C*B] ints = 128 KiB
    float* pooledT = (float*)d_ws;
    int*   pidxT   = (int*)(pooledT + B * C);

    pool_zero_kernel<<<B * C, 256, 0, stream>>>(act, out, pooledT, pidxT);
    topk_scatter_kernel<<<C, 64, 0, stream>>>(pooledT, pidxT, out);
}